// Round 11
// baseline (367.646 us; speedup 1.0000x reference)
//
#include <hip/hip_runtime.h>

#define HID 64
#define NCLS 16
#define NCENT 3
#define NCENTS (NCLS * NCENT)
#define BSHIFT 9               // 512 nodes per bin
#define BINW (1 << BSHIFT)
#define NBINMAX 256            // supports N <= 131072
#define CHUNK 4096             // edges per k_bin/k_count block
#define EPT (CHUNK / 256)
#define NU 16                  // k_agg gather pipeline depth

static inline int ceil_div(int a, int b) { return (a + b - 1) / b; }

__device__ inline unsigned short f2bf(float f) {   // round-to-nearest-even
    unsigned int u = __float_as_uint(f);
    return (unsigned short)((u + 0x7FFFu + ((u >> 16) & 1u)) >> 16);
}
__device__ inline unsigned int pack2bf(float lo, float hi) {
    return (unsigned int)f2bf(lo) | ((unsigned int)f2bf(hi) << 16);
}
__device__ inline float bf2f(unsigned short h) {
    return __uint_as_float(((unsigned int)h) << 16);
}
__device__ inline float bflo(unsigned int u) { return __uint_as_float(u << 16); }
__device__ inline float bfhi(unsigned int u) { return __uint_as_float(u & 0xFFFF0000u); }

// ---- edge binning (counting-sort by dst>>BSHIFT) ------------------------

__global__ void k_count(const int* __restrict__ dst, int* __restrict__ binCnt,
                        int E, int nbins) {
    __shared__ int c[NBINMAX];
    for (int i = threadIdx.x; i < nbins; i += 256) c[i] = 0;
    __syncthreads();
    int e = blockIdx.x * CHUNK + threadIdx.x;
#pragma unroll
    for (int j = 0; j < EPT; j++, e += 256)
        if (e < E) atomicAdd(&c[dst[e] >> BSHIFT], 1);
    __syncthreads();
    for (int i = threadIdx.x; i < nbins; i += 256)
        if (c[i] > 0) atomicAdd(&binCnt[i], c[i]);
}

__global__ void k_binoff(const int* __restrict__ binCnt, int* __restrict__ binBase,
                         int nbins, int E) {
    __shared__ int ts[NBINMAX];
    int t = threadIdx.x;
    int v = (t < nbins) ? binCnt[t] : 0;
    ts[t] = v;
    __syncthreads();
    for (int off = 1; off < NBINMAX; off <<= 1) {
        int x = (t >= off) ? ts[t - off] : 0;
        __syncthreads();
        ts[t] += x;
        __syncthreads();
    }
    if (t < nbins) binBase[t] = ts[t] - v;   // exclusive
    if (t == 0) binBase[nbins] = E;
}

// Stage CHUNK edges in LDS packed by bin; copy out contiguous per-bin segments.
__global__ __launch_bounds__(256) void k_bin(const int* __restrict__ src,
                                             const int* __restrict__ dst,
                                             const int* __restrict__ binBase,
                                             int* __restrict__ binCur,
                                             int2* __restrict__ binned,
                                             int E, int nbins) {
    __shared__ int cnt[NBINMAX], off[NBINMAX], gbase[NBINMAX];
    __shared__ int2 stage[CHUNK];
    const int c0 = blockIdx.x * CHUNK;
    const int tid = threadIdx.x;
    cnt[tid] = 0;
    __syncthreads();
    int sv[EPT], dv[EPT];
#pragma unroll
    for (int j = 0; j < EPT; j++) {
        int e = c0 + j * 256 + tid;
        dv[j] = -1;
        if (e < E) {
            sv[j] = src[e];
            dv[j] = dst[e];
            atomicAdd(&cnt[dv[j] >> BSHIFT], 1);
        }
    }
    __syncthreads();
    off[tid] = cnt[tid];
    __syncthreads();
    for (int o = 1; o < NBINMAX; o <<= 1) {
        int x = (tid >= o) ? off[tid - o] : 0;
        __syncthreads();
        off[tid] += x;
        __syncthreads();
    }
    int excl = off[tid] - cnt[tid];
    __syncthreads();
    off[tid] = excl;
    gbase[tid] = (tid < nbins && cnt[tid] > 0) ? atomicAdd(&binCur[tid], cnt[tid]) : 0;
    cnt[tid] = 0;  // reuse as local cursor
    __syncthreads();
#pragma unroll
    for (int j = 0; j < EPT; j++)
        if (dv[j] >= 0) {
            int b = dv[j] >> BSHIFT;
            int pos = off[b] + atomicAdd(&cnt[b], 1);
            stage[pos] = make_int2(sv[j], dv[j]);
        }
    __syncthreads();
    int tot = min(CHUNK, E - c0);
    for (int i = tid; i < tot; i += 256) {
        int2 v = stage[i];
        int b = v.y >> BSHIFT;
        binned[binBase[b] + gbase[b] + (i - off[b])] = v;
    }
}

// One block per bin: fused hist + local scan + deg/rs/dinv write + col scatter.
__global__ __launch_bounds__(256) void k_fillc2(const int2* __restrict__ binned,
                                                const int* __restrict__ binBase,
                                                int* __restrict__ col,
                                                int* __restrict__ rs_out,
                                                int* __restrict__ deg_out,
                                                float* __restrict__ dinv_out, int N) {
    __shared__ int c[BINW];      // histogram, then cursor
    __shared__ int rsl[BINW];    // per-node row start
    __shared__ int ts[256];
    int b = blockIdx.x;
    int s = binBase[b], e = binBase[b + 1];
    int n0 = b << BSHIFT;
    int t = threadIdx.x;
    c[2 * t] = 0; c[2 * t + 1] = 0;
    __syncthreads();
    for (int i = s + t; i < e; i += 256)
        atomicAdd(&c[binned[i].y - n0], 1);
    __syncthreads();
    int v0 = c[2 * t], v1 = c[2 * t + 1];
    ts[t] = v0 + v1;
    __syncthreads();
    for (int off = 1; off < 256; off <<= 1) {
        int x = (t >= off) ? ts[t - off] : 0;
        __syncthreads();
        ts[t] += x;
        __syncthreads();
    }
    int base = binBase[b] + ts[t] - (v0 + v1);  // exclusive over node pairs
    rsl[2 * t] = base;
    rsl[2 * t + 1] = base + v0;
    int n = n0 + 2 * t;
    if (n < N) {
        deg_out[n] = v0; rs_out[n] = base;
        dinv_out[n] = rsqrtf((float)(v0 + 1));   // +1 self loop
    }
    if (n + 1 < N) {
        deg_out[n + 1] = v1; rs_out[n + 1] = base + v0;
        dinv_out[n + 1] = rsqrtf((float)(v1 + 1));
    }
    c[2 * t] = 0; c[2 * t + 1] = 0;   // reset as cursor
    __syncthreads();
    for (int i = s + t; i < e; i += 256) {
        int2 v = binned[i];
        int lo = v.y - n0;
        int pos = rsl[lo] + atomicAdd(&c[lo], 1);
        col[pos] = v.x;
    }
}

// ---- dense GEMM: out[N,64] = A[N,K] @ W[K,64], bf16 out -----------------
// BF=false: fp32 input (layer 1, K=128). BF=true: bf16 input (layers 2,3).

template <int K, bool BF>
__global__ __launch_bounds__(256) void k_gemm(const void* __restrict__ Ain,
                                              const float* __restrict__ W,
                                              unsigned short* __restrict__ out, int N) {
    __shared__ float Ws[64 * HID];
    __shared__ float As[64][68];
    const int tx = threadIdx.x & 15;
    const int ty = threadIdx.x >> 4;
    const int row0 = blockIdx.x * 64;

    float acc[4][4] = {};

    for (int k0 = 0; k0 < K; k0 += 64) {
        if (k0 > 0) __syncthreads();
        for (int i = threadIdx.x; i < 64 * 16; i += 256)
            ((float4*)Ws)[i] = ((const float4*)(W + (size_t)k0 * HID))[i];
        for (int i = threadIdx.x; i < 64 * 16; i += 256) {
            int r = i >> 4, c = i & 15;
            int row = row0 + r;
            float4 v = {0.f, 0.f, 0.f, 0.f};
            if (row < N) {
                if (BF) {
                    ushort4 u = *(const ushort4*)((const unsigned short*)Ain +
                                                  (size_t)row * K + k0 + 4 * c);
                    v.x = bf2f(u.x); v.y = bf2f(u.y); v.z = bf2f(u.z); v.w = bf2f(u.w);
                } else {
                    v = *(const float4*)((const float*)Ain + (size_t)row * K + k0 + 4 * c);
                }
            }
            *(float4*)&As[r][4 * c] = v;
        }
        __syncthreads();
#pragma unroll 4
        for (int k = 0; k < 64; k++) {
            float4 w = *(const float4*)&Ws[k * HID + 4 * tx];
#pragma unroll
            for (int i = 0; i < 4; i++) {
                float a = As[4 * ty + i][k];
                acc[i][0] = fmaf(a, w.x, acc[i][0]);
                acc[i][1] = fmaf(a, w.y, acc[i][1]);
                acc[i][2] = fmaf(a, w.z, acc[i][2]);
                acc[i][3] = fmaf(a, w.w, acc[i][3]);
            }
        }
    }
#pragma unroll
    for (int i = 0; i < 4; i++) {
        int row = row0 + 4 * ty + i;
        if (row < N) {
            ushort4 v = {f2bf(acc[i][0]), f2bf(acc[i][1]), f2bf(acc[i][2]), f2bf(acc[i][3])};
            *(ushort4*)&out[(size_t)row * HID + 4 * tx] = v;
        }
    }
}

// ---- aggregation: 8-lane group per node, lane = 8 feats (uint4 = 16B) ----
// NU=16-deep gather pipeline. Issue order for vmcnt: col[NU] -> dinv[NU] ->
// gathers[NU] -> FMAs; FMA j waits only on gather j. Masked tail (clamped
// index repeats one row -> L1 hit, no extra HBM traffic).

__global__ void k_agg(const unsigned short* __restrict__ tin,
                      unsigned short* __restrict__ out,
                      const int* __restrict__ rs, const int* __restrict__ deg,
                      const int* __restrict__ col,
                      const float* __restrict__ dinv, const float* __restrict__ bias,
                      int N, int relu) {
    int node = (blockIdx.x * blockDim.x + threadIdx.x) >> 3;
    int l = threadIdx.x & 7;
    if (node >= N) return;
    float di = dinv[node];
    uint4 tb = ((const uint4*)(tin + (size_t)node * HID))[l];
    float s2 = di * di;
    float a0 = s2 * bflo(tb.x), a1 = s2 * bfhi(tb.x);
    float a2 = s2 * bflo(tb.y), a3 = s2 * bfhi(tb.y);
    float a4 = s2 * bflo(tb.z), a5 = s2 * bfhi(tb.z);
    float a6 = s2 * bflo(tb.w), a7 = s2 * bfhi(tb.w);

    int beg = rs[node];
    int cnt = deg[node];
    int last = beg + cnt - 1;
    for (int e = 0; e < cnt; e += NU) {
        int sv[NU];
#pragma unroll
        for (int j = 0; j < NU; j++) {
            int idx = beg + e + j;
            sv[j] = col[idx < last ? idx : last];
        }
        float dvv[NU];
#pragma unroll
        for (int j = 0; j < NU; j++) dvv[j] = dinv[sv[j]];
        uint4 vv[NU];
#pragma unroll
        for (int j = 0; j < NU; j++) vv[j] = ((const uint4*)(tin + (size_t)sv[j] * HID))[l];
#pragma unroll
        for (int j = 0; j < NU; j++) {
            float w = (e + j < cnt) ? dvv[j] * di : 0.0f;
            a0 = fmaf(w, bflo(vv[j].x), a0); a1 = fmaf(w, bfhi(vv[j].x), a1);
            a2 = fmaf(w, bflo(vv[j].y), a2); a3 = fmaf(w, bfhi(vv[j].y), a3);
            a4 = fmaf(w, bflo(vv[j].z), a4); a5 = fmaf(w, bfhi(vv[j].z), a5);
            a6 = fmaf(w, bflo(vv[j].w), a6); a7 = fmaf(w, bfhi(vv[j].w), a7);
        }
    }
    float4 b0 = ((const float4*)bias)[2 * l];
    float4 b1 = ((const float4*)bias)[2 * l + 1];
    a0 += b0.x; a1 += b0.y; a2 += b0.z; a3 += b0.w;
    a4 += b1.x; a5 += b1.y; a6 += b1.z; a7 += b1.w;
    if (relu) {
        a0 = fmaxf(a0, 0.f); a1 = fmaxf(a1, 0.f); a2 = fmaxf(a2, 0.f); a3 = fmaxf(a3, 0.f);
        a4 = fmaxf(a4, 0.f); a5 = fmaxf(a5, 0.f); a6 = fmaxf(a6, 0.f); a7 = fmaxf(a7, 0.f);
    }
    uint4 o;
    o.x = pack2bf(a0, a1); o.y = pack2bf(a2, a3);
    o.z = pack2bf(a4, a5); o.w = pack2bf(a6, a7);
    ((uint4*)(out + (size_t)node * HID))[l] = o;
}

// ---- fused mean-pool + centroid-distance head (bf16 input) --------------

__global__ void k_pool_head(const unsigned short* __restrict__ h,
                            const int* __restrict__ batch,
                            const float* __restrict__ cent, const float* __restrict__ rbias,
                            float* __restrict__ out, int N) {
    int g = blockIdx.x;
    int lo = 0, hi = N;
    while (lo < hi) { int mid = (lo + hi) >> 1; if (batch[mid] < g) lo = mid + 1; else hi = mid; }
    int s = lo;
    lo = 0; hi = N;
    while (lo < hi) { int mid = (lo + hi) >> 1; if (batch[mid] < g + 1) lo = mid + 1; else hi = mid; }
    int e = lo;

    __shared__ float part[4][HID];
    __shared__ float embS[HID];
    __shared__ float dS[NCENTS];
    __shared__ float dpcS[NCLS];

    int lane = threadIdx.x & 63, wid = threadIdx.x >> 6;
    float acc = 0.0f;
    for (int i = s + wid; i < e; i += 4) acc += bf2f(h[(size_t)i * HID + lane]);
    part[wid][lane] = acc;
    __syncthreads();
    if (wid == 0) {
        float v = part[0][lane] + part[1][lane] + part[2][lane] + part[3][lane];
        embS[lane] = v / fmaxf((float)(e - s), 1.0f);
    }
    __syncthreads();
    if (threadIdx.x < NCENTS) {
        const float* c = cent + threadIdx.x * HID;
        float d = 0.0f;
        for (int k = 0; k < HID; k++) { float df = embS[k] - c[k]; d = fmaf(df, df, d); }
        dS[threadIdx.x] = d;
    }
    __syncthreads();
    if (threadIdx.x < NCLS) {
        float m = fminf(dS[threadIdx.x * 3],
                        fminf(dS[threadIdx.x * 3 + 1], dS[threadIdx.x * 3 + 2]));
        dpcS[threadIdx.x] = m;
        out[g * (NCLS + 1) + threadIdx.x] = -m;
    }
    __syncthreads();
    if (threadIdx.x == 0) {
        float m = dpcS[0];
        for (int i = 1; i < NCLS; i++) m = fminf(m, dpcS[i]);
        out[g * (NCLS + 1) + NCLS] = m - rbias[0];
    }
}

// ---- launch -------------------------------------------------------------

extern "C" void kernel_launch(void* const* d_in, const int* in_sizes, int n_in,
                              void* d_out, int out_size, void* d_ws, size_t ws_size,
                              hipStream_t stream) {
    const float* x    = (const float*)d_in[0];
    const int*   ei   = (const int*)d_in[1];   // [2, E]: row0 = src, row1 = dst
    const int*   bat  = (const int*)d_in[2];
    const float* W1   = (const float*)d_in[3];
    const float* b1   = (const float*)d_in[4];
    const float* W2   = (const float*)d_in[5];
    const float* b2   = (const float*)d_in[6];
    const float* W3   = (const float*)d_in[7];
    const float* b3   = (const float*)d_in[8];
    const float* cent = (const float*)d_in[9];
    const float* rb   = (const float*)d_in[10];
    float* out = (float*)d_out;

    const int N = in_sizes[0] / 128;
    const int E = in_sizes[1] / 2;
    const int nbins = (N + BINW - 1) >> BSHIFT;

    char* p = (char*)d_ws;
    unsigned short* A  = (unsigned short*)p; p += (size_t)N * HID * 2;  // bf16 gather table
    unsigned short* Bb = (unsigned short*)p; p += (size_t)N * HID * 2;  // bf16 agg output
    int2*  binned = (int2*)p;  p += (size_t)E * 8;
    int*   col    = (int*)p;   p += (size_t)E * 4;
    float* dinv   = (float*)p; p += (size_t)N * 4;
    int*   rs     = (int*)p;   p += (size_t)N * 4;
    int*   deg    = (int*)p;   p += (size_t)N * 4;
    int*   binBase= (int*)p;   p += (NBINMAX + 2) * 4;
    // zeroed region: binCnt | binCur
    int*   binCnt = (int*)p;   p += NBINMAX * 4;
    int*   binCur = (int*)p;   p += NBINMAX * 4;

    hipMemsetAsync(binCnt, 0, 2 * NBINMAX * 4, stream);

    k_count<<<ceil_div(E, CHUNK), 256, 0, stream>>>(ei + E, binCnt, E, nbins);
    k_binoff<<<1, 256, 0, stream>>>(binCnt, binBase, nbins, E);
    k_bin<<<ceil_div(E, CHUNK), 256, 0, stream>>>(ei, ei + E, binBase, binCur, binned, E, nbins);
    k_fillc2<<<nbins, 256, 0, stream>>>(binned, binBase, col, rs, deg, dinv, N);

    k_gemm<128, false><<<ceil_div(N, 64), 256, 0, stream>>>(x, W1, A, N);
    k_agg<<<ceil_div(N * 8, 256), 256, 0, stream>>>(A, Bb, rs, deg, col, dinv, b1, N, 1);
    k_gemm<64, true><<<ceil_div(N, 64), 256, 0, stream>>>(Bb, W2, A, N);
    k_agg<<<ceil_div(N * 8, 256), 256, 0, stream>>>(A, Bb, rs, deg, col, dinv, b2, N, 1);
    k_gemm<64, true><<<ceil_div(N, 64), 256, 0, stream>>>(Bb, W3, A, N);
    k_agg<<<ceil_div(N * 8, 256), 256, 0, stream>>>(A, Bb, rs, deg, col, dinv, b3, N, 0);

    k_pool_head<<<1024, 256, 0, stream>>>(Bb, bat, cent, rb, out, N);
}

// Round 12
// 352.865 us; speedup vs baseline: 1.0419x; 1.0419x over previous
//
#include <hip/hip_runtime.h>

#define HID 64
#define NCLS 16
#define NCENT 3
#define NCENTS (NCLS * NCENT)
#define BSHIFT 9               // 512 nodes per bin
#define BINW (1 << BSHIFT)
#define NBINMAX 256            // supports N <= 131072
#define CHUNK 4096             // edges per k_bin/k_count block
#define EPT (CHUNK / 256)
#define NU 8                   // k_agg gather pipeline depth
                               // (measured optimum: NU=16 regressed -4% via
                               //  VGPR->occupancy loss; NU=8 is the sweet spot)

static inline int ceil_div(int a, int b) { return (a + b - 1) / b; }

__device__ inline unsigned short f2bf(float f) {   // round-to-nearest-even
    unsigned int u = __float_as_uint(f);
    return (unsigned short)((u + 0x7FFFu + ((u >> 16) & 1u)) >> 16);
}
__device__ inline unsigned int pack2bf(float lo, float hi) {
    return (unsigned int)f2bf(lo) | ((unsigned int)f2bf(hi) << 16);
}
__device__ inline float bf2f(unsigned short h) {
    return __uint_as_float(((unsigned int)h) << 16);
}
__device__ inline float bflo(unsigned int u) { return __uint_as_float(u << 16); }
__device__ inline float bfhi(unsigned int u) { return __uint_as_float(u & 0xFFFF0000u); }

// ---- edge binning (counting-sort by dst>>BSHIFT) ------------------------

__global__ void k_count(const int* __restrict__ dst, int* __restrict__ binCnt,
                        int E, int nbins) {
    __shared__ int c[NBINMAX];
    for (int i = threadIdx.x; i < nbins; i += 256) c[i] = 0;
    __syncthreads();
    int e = blockIdx.x * CHUNK + threadIdx.x;
#pragma unroll
    for (int j = 0; j < EPT; j++, e += 256)
        if (e < E) atomicAdd(&c[dst[e] >> BSHIFT], 1);
    __syncthreads();
    for (int i = threadIdx.x; i < nbins; i += 256)
        if (c[i] > 0) atomicAdd(&binCnt[i], c[i]);
}

__global__ void k_binoff(const int* __restrict__ binCnt, int* __restrict__ binBase,
                         int nbins, int E) {
    __shared__ int ts[NBINMAX];
    int t = threadIdx.x;
    int v = (t < nbins) ? binCnt[t] : 0;
    ts[t] = v;
    __syncthreads();
    for (int off = 1; off < NBINMAX; off <<= 1) {
        int x = (t >= off) ? ts[t - off] : 0;
        __syncthreads();
        ts[t] += x;
        __syncthreads();
    }
    if (t < nbins) binBase[t] = ts[t] - v;   // exclusive
    if (t == 0) binBase[nbins] = E;
}

// Stage CHUNK edges in LDS packed by bin; copy out contiguous per-bin segments.
__global__ __launch_bounds__(256) void k_bin(const int* __restrict__ src,
                                             const int* __restrict__ dst,
                                             const int* __restrict__ binBase,
                                             int* __restrict__ binCur,
                                             int2* __restrict__ binned,
                                             int E, int nbins) {
    __shared__ int cnt[NBINMAX], off[NBINMAX], gbase[NBINMAX];
    __shared__ int2 stage[CHUNK];
    const int c0 = blockIdx.x * CHUNK;
    const int tid = threadIdx.x;
    cnt[tid] = 0;
    __syncthreads();
    int sv[EPT], dv[EPT];
#pragma unroll
    for (int j = 0; j < EPT; j++) {
        int e = c0 + j * 256 + tid;
        dv[j] = -1;
        if (e < E) {
            sv[j] = src[e];
            dv[j] = dst[e];
            atomicAdd(&cnt[dv[j] >> BSHIFT], 1);
        }
    }
    __syncthreads();
    off[tid] = cnt[tid];
    __syncthreads();
    for (int o = 1; o < NBINMAX; o <<= 1) {
        int x = (tid >= o) ? off[tid - o] : 0;
        __syncthreads();
        off[tid] += x;
        __syncthreads();
    }
    int excl = off[tid] - cnt[tid];
    __syncthreads();
    off[tid] = excl;
    gbase[tid] = (tid < nbins && cnt[tid] > 0) ? atomicAdd(&binCur[tid], cnt[tid]) : 0;
    cnt[tid] = 0;  // reuse as local cursor
    __syncthreads();
#pragma unroll
    for (int j = 0; j < EPT; j++)
        if (dv[j] >= 0) {
            int b = dv[j] >> BSHIFT;
            int pos = off[b] + atomicAdd(&cnt[b], 1);
            stage[pos] = make_int2(sv[j], dv[j]);
        }
    __syncthreads();
    int tot = min(CHUNK, E - c0);
    for (int i = tid; i < tot; i += 256) {
        int2 v = stage[i];
        int b = v.y >> BSHIFT;
        binned[binBase[b] + gbase[b] + (i - off[b])] = v;
    }
}

// One block per bin: fused hist + local scan + deg/rs/dinv write + col scatter.
__global__ __launch_bounds__(256) void k_fillc2(const int2* __restrict__ binned,
                                                const int* __restrict__ binBase,
                                                int* __restrict__ col,
                                                int* __restrict__ rs_out,
                                                int* __restrict__ deg_out,
                                                float* __restrict__ dinv_out, int N) {
    __shared__ int c[BINW];      // histogram, then cursor
    __shared__ int rsl[BINW];    // per-node row start
    __shared__ int ts[256];
    int b = blockIdx.x;
    int s = binBase[b], e = binBase[b + 1];
    int n0 = b << BSHIFT;
    int t = threadIdx.x;
    c[2 * t] = 0; c[2 * t + 1] = 0;
    __syncthreads();
    for (int i = s + t; i < e; i += 256)
        atomicAdd(&c[binned[i].y - n0], 1);
    __syncthreads();
    int v0 = c[2 * t], v1 = c[2 * t + 1];
    ts[t] = v0 + v1;
    __syncthreads();
    for (int off = 1; off < 256; off <<= 1) {
        int x = (t >= off) ? ts[t - off] : 0;
        __syncthreads();
        ts[t] += x;
        __syncthreads();
    }
    int base = binBase[b] + ts[t] - (v0 + v1);  // exclusive over node pairs
    rsl[2 * t] = base;
    rsl[2 * t + 1] = base + v0;
    int n = n0 + 2 * t;
    if (n < N) {
        deg_out[n] = v0; rs_out[n] = base;
        dinv_out[n] = rsqrtf((float)(v0 + 1));   // +1 self loop
    }
    if (n + 1 < N) {
        deg_out[n + 1] = v1; rs_out[n + 1] = base + v0;
        dinv_out[n + 1] = rsqrtf((float)(v1 + 1));
    }
    c[2 * t] = 0; c[2 * t + 1] = 0;   // reset as cursor
    __syncthreads();
    for (int i = s + t; i < e; i += 256) {
        int2 v = binned[i];
        int lo = v.y - n0;
        int pos = rsl[lo] + atomicAdd(&c[lo], 1);
        col[pos] = v.x;
    }
}

// ---- dense GEMM: out[N,64] = A[N,K] @ W[K,64], bf16 out -----------------
// BF=false: fp32 input (layer 1, K=128). BF=true: bf16 input (layers 2,3).

template <int K, bool BF>
__global__ __launch_bounds__(256) void k_gemm(const void* __restrict__ Ain,
                                              const float* __restrict__ W,
                                              unsigned short* __restrict__ out, int N) {
    __shared__ float Ws[64 * HID];
    __shared__ float As[64][68];
    const int tx = threadIdx.x & 15;
    const int ty = threadIdx.x >> 4;
    const int row0 = blockIdx.x * 64;

    float acc[4][4] = {};

    for (int k0 = 0; k0 < K; k0 += 64) {
        if (k0 > 0) __syncthreads();
        for (int i = threadIdx.x; i < 64 * 16; i += 256)
            ((float4*)Ws)[i] = ((const float4*)(W + (size_t)k0 * HID))[i];
        for (int i = threadIdx.x; i < 64 * 16; i += 256) {
            int r = i >> 4, c = i & 15;
            int row = row0 + r;
            float4 v = {0.f, 0.f, 0.f, 0.f};
            if (row < N) {
                if (BF) {
                    ushort4 u = *(const ushort4*)((const unsigned short*)Ain +
                                                  (size_t)row * K + k0 + 4 * c);
                    v.x = bf2f(u.x); v.y = bf2f(u.y); v.z = bf2f(u.z); v.w = bf2f(u.w);
                } else {
                    v = *(const float4*)((const float*)Ain + (size_t)row * K + k0 + 4 * c);
                }
            }
            *(float4*)&As[r][4 * c] = v;
        }
        __syncthreads();
#pragma unroll 4
        for (int k = 0; k < 64; k++) {
            float4 w = *(const float4*)&Ws[k * HID + 4 * tx];
#pragma unroll
            for (int i = 0; i < 4; i++) {
                float a = As[4 * ty + i][k];
                acc[i][0] = fmaf(a, w.x, acc[i][0]);
                acc[i][1] = fmaf(a, w.y, acc[i][1]);
                acc[i][2] = fmaf(a, w.z, acc[i][2]);
                acc[i][3] = fmaf(a, w.w, acc[i][3]);
            }
        }
    }
#pragma unroll
    for (int i = 0; i < 4; i++) {
        int row = row0 + 4 * ty + i;
        if (row < N) {
            ushort4 v = {f2bf(acc[i][0]), f2bf(acc[i][1]), f2bf(acc[i][2]), f2bf(acc[i][3])};
            *(ushort4*)&out[(size_t)row * HID + 4 * tx] = v;
        }
    }
}

// ---- aggregation: 8-lane group per node, lane = 8 feats (uint4 = 16B) ----
// NU=8-deep gather pipeline. Issue order for vmcnt: col[NU] -> dinv[NU] ->
// gathers[NU] -> FMAs; FMA j waits only on gather j. Masked tail (clamped
// index repeats one row -> L1 hit, no extra HBM traffic).

__global__ void k_agg(const unsigned short* __restrict__ tin,
                      unsigned short* __restrict__ out,
                      const int* __restrict__ rs, const int* __restrict__ deg,
                      const int* __restrict__ col,
                      const float* __restrict__ dinv, const float* __restrict__ bias,
                      int N, int relu) {
    int node = (blockIdx.x * blockDim.x + threadIdx.x) >> 3;
    int l = threadIdx.x & 7;
    if (node >= N) return;
    float di = dinv[node];
    uint4 tb = ((const uint4*)(tin + (size_t)node * HID))[l];
    float s2 = di * di;
    float a0 = s2 * bflo(tb.x), a1 = s2 * bfhi(tb.x);
    float a2 = s2 * bflo(tb.y), a3 = s2 * bfhi(tb.y);
    float a4 = s2 * bflo(tb.z), a5 = s2 * bfhi(tb.z);
    float a6 = s2 * bflo(tb.w), a7 = s2 * bfhi(tb.w);

    int beg = rs[node];
    int cnt = deg[node];
    int last = beg + cnt - 1;
    for (int e = 0; e < cnt; e += NU) {
        int sv[NU];
#pragma unroll
        for (int j = 0; j < NU; j++) {
            int idx = beg + e + j;
            sv[j] = col[idx < last ? idx : last];
        }
        float dvv[NU];
#pragma unroll
        for (int j = 0; j < NU; j++) dvv[j] = dinv[sv[j]];
        uint4 vv[NU];
#pragma unroll
        for (int j = 0; j < NU; j++) vv[j] = ((const uint4*)(tin + (size_t)sv[j] * HID))[l];
#pragma unroll
        for (int j = 0; j < NU; j++) {
            float w = (e + j < cnt) ? dvv[j] * di : 0.0f;
            a0 = fmaf(w, bflo(vv[j].x), a0); a1 = fmaf(w, bfhi(vv[j].x), a1);
            a2 = fmaf(w, bflo(vv[j].y), a2); a3 = fmaf(w, bfhi(vv[j].y), a3);
            a4 = fmaf(w, bflo(vv[j].z), a4); a5 = fmaf(w, bfhi(vv[j].z), a5);
            a6 = fmaf(w, bflo(vv[j].w), a6); a7 = fmaf(w, bfhi(vv[j].w), a7);
        }
    }
    float4 b0 = ((const float4*)bias)[2 * l];
    float4 b1 = ((const float4*)bias)[2 * l + 1];
    a0 += b0.x; a1 += b0.y; a2 += b0.z; a3 += b0.w;
    a4 += b1.x; a5 += b1.y; a6 += b1.z; a7 += b1.w;
    if (relu) {
        a0 = fmaxf(a0, 0.f); a1 = fmaxf(a1, 0.f); a2 = fmaxf(a2, 0.f); a3 = fmaxf(a3, 0.f);
        a4 = fmaxf(a4, 0.f); a5 = fmaxf(a5, 0.f); a6 = fmaxf(a6, 0.f); a7 = fmaxf(a7, 0.f);
    }
    uint4 o;
    o.x = pack2bf(a0, a1); o.y = pack2bf(a2, a3);
    o.z = pack2bf(a4, a5); o.w = pack2bf(a6, a7);
    ((uint4*)(out + (size_t)node * HID))[l] = o;
}

// ---- fused mean-pool + centroid-distance head (bf16 input) --------------

__global__ void k_pool_head(const unsigned short* __restrict__ h,
                            const int* __restrict__ batch,
                            const float* __restrict__ cent, const float* __restrict__ rbias,
                            float* __restrict__ out, int N) {
    int g = blockIdx.x;
    int lo = 0, hi = N;
    while (lo < hi) { int mid = (lo + hi) >> 1; if (batch[mid] < g) lo = mid + 1; else hi = mid; }
    int s = lo;
    lo = 0; hi = N;
    while (lo < hi) { int mid = (lo + hi) >> 1; if (batch[mid] < g + 1) lo = mid + 1; else hi = mid; }
    int e = lo;

    __shared__ float part[4][HID];
    __shared__ float embS[HID];
    __shared__ float dS[NCENTS];
    __shared__ float dpcS[NCLS];

    int lane = threadIdx.x & 63, wid = threadIdx.x >> 6;
    float acc = 0.0f;
    for (int i = s + wid; i < e; i += 4) acc += bf2f(h[(size_t)i * HID + lane]);
    part[wid][lane] = acc;
    __syncthreads();
    if (wid == 0) {
        float v = part[0][lane] + part[1][lane] + part[2][lane] + part[3][lane];
        embS[lane] = v / fmaxf((float)(e - s), 1.0f);
    }
    __syncthreads();
    if (threadIdx.x < NCENTS) {
        const float* c = cent + threadIdx.x * HID;
        float d = 0.0f;
        for (int k = 0; k < HID; k++) { float df = embS[k] - c[k]; d = fmaf(df, df, d); }
        dS[threadIdx.x] = d;
    }
    __syncthreads();
    if (threadIdx.x < NCLS) {
        float m = fminf(dS[threadIdx.x * 3],
                        fminf(dS[threadIdx.x * 3 + 1], dS[threadIdx.x * 3 + 2]));
        dpcS[threadIdx.x] = m;
        out[g * (NCLS + 1) + threadIdx.x] = -m;
    }
    __syncthreads();
    if (threadIdx.x == 0) {
        float m = dpcS[0];
        for (int i = 1; i < NCLS; i++) m = fminf(m, dpcS[i]);
        out[g * (NCLS + 1) + NCLS] = m - rbias[0];
    }
}

// ---- launch -------------------------------------------------------------

extern "C" void kernel_launch(void* const* d_in, const int* in_sizes, int n_in,
                              void* d_out, int out_size, void* d_ws, size_t ws_size,
                              hipStream_t stream) {
    const float* x    = (const float*)d_in[0];
    const int*   ei   = (const int*)d_in[1];   // [2, E]: row0 = src, row1 = dst
    const int*   bat  = (const int*)d_in[2];
    const float* W1   = (const float*)d_in[3];
    const float* b1   = (const float*)d_in[4];
    const float* W2   = (const float*)d_in[5];
    const float* b2   = (const float*)d_in[6];
    const float* W3   = (const float*)d_in[7];
    const float* b3   = (const float*)d_in[8];
    const float* cent = (const float*)d_in[9];
    const float* rb   = (const float*)d_in[10];
    float* out = (float*)d_out;

    const int N = in_sizes[0] / 128;
    const int E = in_sizes[1] / 2;
    const int nbins = (N + BINW - 1) >> BSHIFT;

    char* p = (char*)d_ws;
    unsigned short* A  = (unsigned short*)p; p += (size_t)N * HID * 2;  // bf16 gather table
    unsigned short* Bb = (unsigned short*)p; p += (size_t)N * HID * 2;  // bf16 agg output
    int2*  binned = (int2*)p;  p += (size_t)E * 8;
    int*   col    = (int*)p;   p += (size_t)E * 4;
    float* dinv   = (float*)p; p += (size_t)N * 4;
    int*   rs     = (int*)p;   p += (size_t)N * 4;
    int*   deg    = (int*)p;   p += (size_t)N * 4;
    int*   binBase= (int*)p;   p += (NBINMAX + 2) * 4;
    // zeroed region: binCnt | binCur
    int*   binCnt = (int*)p;   p += NBINMAX * 4;
    int*   binCur = (int*)p;   p += NBINMAX * 4;

    hipMemsetAsync(binCnt, 0, 2 * NBINMAX * 4, stream);

    k_count<<<ceil_div(E, CHUNK), 256, 0, stream>>>(ei + E, binCnt, E, nbins);
    k_binoff<<<1, 256, 0, stream>>>(binCnt, binBase, nbins, E);
    k_bin<<<ceil_div(E, CHUNK), 256, 0, stream>>>(ei, ei + E, binBase, binCur, binned, E, nbins);
    k_fillc2<<<nbins, 256, 0, stream>>>(binned, binBase, col, rs, deg, dinv, N);

    k_gemm<128, false><<<ceil_div(N, 64), 256, 0, stream>>>(x, W1, A, N);
    k_agg<<<ceil_div(N * 8, 256), 256, 0, stream>>>(A, Bb, rs, deg, col, dinv, b1, N, 1);
    k_gemm<64, true><<<ceil_div(N, 64), 256, 0, stream>>>(Bb, W2, A, N);
    k_agg<<<ceil_div(N * 8, 256), 256, 0, stream>>>(A, Bb, rs, deg, col, dinv, b2, N, 1);
    k_gemm<64, true><<<ceil_div(N, 64), 256, 0, stream>>>(Bb, W3, A, N);
    k_agg<<<ceil_div(N * 8, 256), 256, 0, stream>>>(A, Bb, rs, deg, col, dinv, b3, N, 0);

    k_pool_head<<<1024, 256, 0, stream>>>(Bb, bat, cent, rb, out, N);
}